// Round 1
// baseline (1950.983 us; speedup 1.0000x reference)
//
#include <hip/hip_runtime.h>
#include <hip/hip_bf16.h>

#define N_NODES 50000
#define N_REL   16
#define DIM     128
#define NBLK    4
#define BS      32
#define N_EDGES 800000

// ---------------------------------------------------------------------------
// Kernel 1: count edges per (dst, rel) pair -> cnt[N*R] (int)
// ---------------------------------------------------------------------------
__global__ __launch_bounds__(256) void count_kernel(const int* __restrict__ dst,
                                                    const int* __restrict__ et,
                                                    int* __restrict__ cnt, int E) {
    int e = blockIdx.x * 256 + threadIdx.x;
    if (e < E) atomicAdd(&cnt[dst[e] * N_REL + et[e]], 1);
}

// ---------------------------------------------------------------------------
// Kernel 2: out[n][:] = bias + act(x[n]) @ root   (initializes the output;
// edge kernel then atomically accumulates messages on top)
// Block: 256 threads, handles 32 nodes x 64 output cols (grid.y = col half).
// LDS: root half 32KB + x rows 16KB = 48KB.
// ---------------------------------------------------------------------------
template<bool RELU>
__global__ __launch_bounds__(256) void dense_kernel(const float* __restrict__ x,
                                                    const float* __restrict__ root,
                                                    const float* __restrict__ bias,
                                                    float* __restrict__ out, int Ntot) {
    __shared__ float root_sh[DIM * 64];   // [k][j_local]  32KB
    __shared__ float x_sh[32 * DIM];      // [n_local][k]  16KB

    const int jhalf = blockIdx.y;         // 0 or 1
    const int base  = blockIdx.x * 32;
    const int nn    = min(32, Ntot - base);

    // stage root half: root_sh[row*64+col] = root[row*128 + jhalf*64 + col]
    for (int idx = threadIdx.x * 4; idx < DIM * 64; idx += 1024) {
        int row = idx >> 6, col = idx & 63;
        *(float4*)&root_sh[idx] = *(const float4*)&root[row * DIM + jhalf * 64 + col];
    }
    // stage x rows (apply activation here for layer-2 input)
    for (int idx = threadIdx.x * 4; idx < nn * DIM; idx += 1024) {
        float4 v = *(const float4*)&x[base * DIM + idx];
        if (RELU) {
            v.x = fmaxf(v.x, 0.f); v.y = fmaxf(v.y, 0.f);
            v.z = fmaxf(v.z, 0.f); v.w = fmaxf(v.w, 0.f);
        }
        *(float4*)&x_sh[idx] = v;
    }
    __syncthreads();

    const int jl   = threadIdx.x & 63;    // 0..63 (lane)
    const int wave = threadIdx.x >> 6;    // 0..3
    const float bj = bias[jhalf * 64 + jl];

    for (int nl = wave; nl < nn; nl += 4) {
        float acc = bj;
#pragma unroll 16
        for (int k = 0; k < DIM; ++k)
            acc = fmaf(x_sh[nl * DIM + k], root_sh[k * 64 + jl], acc);
        out[(base + nl) * DIM + jhalf * 64 + jl] = acc;
    }
}

// ---------------------------------------------------------------------------
// Kernel 3: per-edge block-diagonal transform + normalized scatter-add.
// grid.y = b (block column, 0..3). LDS stages W[r][b] for all 16 relations
// (16*32*32 fp32 = 64KB). Each half-wave (32 lanes) processes one edge:
// lane o computes msg[b*32+o] = sum_i x[src][b*32+i] * W[r][b][i][o].
// ---------------------------------------------------------------------------
template<bool RELU>
__global__ __launch_bounds__(256) void edge_kernel(const int* __restrict__ src,
                                                   const int* __restrict__ dstv,
                                                   const int* __restrict__ et,
                                                   const float* __restrict__ x,
                                                   const float* __restrict__ W,
                                                   const int* __restrict__ cnt,
                                                   float* __restrict__ out, int E) {
    __shared__ float Wsh[N_REL * BS * BS];   // 64KB
    const int bblk = blockIdx.y;

    // stage W[:, bblk, :, :]
    for (int idx = threadIdx.x * 4; idx < N_REL * BS * BS; idx += 1024) {
        int r = idx >> 10, rest = idx & 1023;
        *(float4*)&Wsh[idx] = *(const float4*)&W[(r * NBLK + bblk) * 1024 + rest];
    }
    __syncthreads();

    const int wave = threadIdx.x >> 6;   // 0..3
    const int lane = threadIdx.x & 63;
    const int half = lane >> 5;          // 0/1: which edge of the pair
    const int o    = lane & 31;          // output index within block

    const int stride = gridDim.x * 8;    // 4 waves * 2 edges each
    for (int e = blockIdx.x * 8 + wave * 2 + half; e < E; e += stride) {
        const int s = src[e];
        const int v = dstv[e];
        const int r = et[e];
        const float cn   = (float)cnt[v * N_REL + r];
        const float norm = 1.0f / fmaxf(cn, 1.0f);

        float xv = x[s * DIM + bblk * BS + o];
        if (RELU) xv = fmaxf(xv, 0.f);

        const float* wr = &Wsh[r * (BS * BS)];
        float acc0 = 0.f, acc1 = 0.f;
#pragma unroll
        for (int i = 0; i < BS; i += 2) {
            float xi0 = __shfl(xv, i,     32);
            float xi1 = __shfl(xv, i + 1, 32);
            acc0 = fmaf(xi0, wr[i * BS + o],       acc0);
            acc1 = fmaf(xi1, wr[(i + 1) * BS + o], acc1);
        }
        unsafeAtomicAdd(&out[v * DIM + bblk * BS + o], (acc0 + acc1) * norm);
    }
}

// ---------------------------------------------------------------------------
extern "C" void kernel_launch(void* const* d_in, const int* in_sizes, int n_in,
                              void* d_out, int out_size, void* d_ws, size_t ws_size,
                              hipStream_t stream) {
    const int*   edge_index = (const int*)d_in[0];
    const int*   src   = edge_index;             // row 0
    const int*   dstv  = edge_index + N_EDGES;   // row 1
    const int*   et    = (const int*)d_in[1];
    const float* x0    = (const float*)d_in[2];
    const float* W1    = (const float*)d_in[3];
    const float* root1 = (const float*)d_in[4];
    const float* bias1 = (const float*)d_in[5];
    const float* W2    = (const float*)d_in[6];
    const float* root2 = (const float*)d_in[7];
    const float* bias2 = (const float*)d_in[8];
    float* out = (float*)d_out;

    float* h   = (float*)d_ws;                                   // N*D fp32
    int*   cnt = (int*)((char*)d_ws + (size_t)N_NODES * DIM * 4); // N*R int

    // zero the (dst,rel) counters every call (harness does not re-poison)
    hipMemsetAsync(cnt, 0, (size_t)N_NODES * N_REL * sizeof(int), stream);
    count_kernel<<<(N_EDGES + 255) / 256, 256, 0, stream>>>(dstv, et, cnt, N_EDGES);

    dim3 dgrid((N_NODES + 31) / 32, 2);
    dim3 egrid(512, NBLK);

    // ---- layer 1: h = x0 @ root1 + bias1 + scatter(W1-msgs)  (pre-ReLU) ----
    dense_kernel<false><<<dgrid, 256, 0, stream>>>(x0, root1, bias1, h, N_NODES);
    edge_kernel<false><<<egrid, 256, 0, stream>>>(src, dstv, et, x0, W1, cnt, h, N_EDGES);

    // ---- layer 2: out = relu(h) @ root2 + bias2 + scatter(W2-msgs on relu(h))
    dense_kernel<true><<<dgrid, 256, 0, stream>>>(h, root2, bias2, out, N_NODES);
    edge_kernel<true><<<egrid, 256, 0, stream>>>(src, dstv, et, h, W2, cnt, out, N_EDGES);
}